// Round 4
// baseline (149.322 us; speedup 1.0000x reference)
//
#include <hip/hip_runtime.h>

// LocalDecoder: per-edge gather + 2 stacked MLPs (256->64->64->1), bf16 MFMA.
//
// ws layout (bytes):
//   OFF_W1: bf16 W1frag[2][5][4][64][8]  (f, kk, nn, lane, j)  = 40960
//   OFF_W2: bf16 W2frag[2][2][4][64][8]                        = 16384
//   OFF_B1: f32 bias1p[2][64]  (b1 + h_global/enc_global folded)
//   OFF_B2: f32 b2[2][64];  OFF_W3: f32 w3[2][64];  OFF_B3: f32 b3[2]
//   OFF_CNT: u32 dynamic chunk counter (re-zeroed by prep_all every launch)

#define OFF_W1 0
#define OFF_W2 40960
#define OFF_B1 57344
#define OFF_B2 57856
#define OFF_W3 58368
#define OFF_B3 58880
#define OFF_CNT 59392
#define H1_OFF 58944            // per-wave h1 scratch [16][72] bf16 = 2304 B
#define NWAVE 8
#define LDS_TOTAL (H1_OFF + NWAVE * 2304)
#define PREP_W_BLOCKS 114

typedef __attribute__((ext_vector_type(8))) short bf16x8;
typedef __attribute__((ext_vector_type(4))) float f32x4;

__device__ inline short f2bf(float f) {
    unsigned u = __builtin_bit_cast(unsigned, f);
    u += 0x7FFFu + ((u >> 16) & 1u);      // round-to-nearest-even
    return (short)(u >> 16);
}

__device__ inline float4 ld4(const float* p, bool v) {
    if (v) return *(const float4*)p;
    return make_float4(0.f, 0.f, 0.f, 0.f);
}

__device__ inline bf16x8 pack8(float4 a, float4 b) {
    bf16x8 r;
    r[0] = f2bf(a.x); r[1] = f2bf(a.y); r[2] = f2bf(a.z); r[3] = f2bf(a.w);
    r[4] = f2bf(b.x); r[5] = f2bf(b.y); r[6] = f2bf(b.z); r[7] = f2bf(b.w);
    return r;
}

// ---------------- prep: W swizzle + bias fold + counter reset
__global__ void prep_all(const float* __restrict__ W1, const float* __restrict__ b1,
                         const float* __restrict__ W2, const float* __restrict__ b2,
                         const float* __restrict__ W3, const float* __restrict__ b3,
                         const float* __restrict__ h_global, const float* __restrict__ enc_global,
                         char* __restrict__ ws) {
    int idx = blockIdx.x * 256 + threadIdx.x;
    if (idx == 0) *(unsigned*)(ws + OFF_CNT) = 0u;       // dynamic-sched counter
    short* w1f = (short*)(ws + OFF_W1);
    short* w2f = (short*)(ws + OFF_W2);
    float* bp1 = (float*)(ws + OFF_B1);
    float* bp2 = (float*)(ws + OFF_B2);
    float* wp3 = (float*)(ws + OFF_W3);
    float* bp3 = (float*)(ws + OFF_B3);
    if (idx < 20480) {                       // W1 fragments, K dims: [gf 0:64 | gt 64:128 | encl 128:160]
        int f = idx / 10240, r0 = idx % 10240;
        int kk = r0 / 2048, r1 = r0 % 2048;
        int nn = r1 / 512,  r2 = r1 % 512;
        int l = r2 / 8,     j = r2 % 8;
        int kt = kk * 32 + (l >> 4) * 8 + j;             // 0..159
        int r = (kt < 128) ? kt : kt + 64;               // enc_local rows live at 192..223
        int c = nn * 16 + (l & 15);
        w1f[idx] = f2bf(W1[(f * 256 + r) * 64 + c]);
    } else if (idx < 28672) {                // W2 fragments
        int i2 = idx - 20480;
        int f = i2 / 4096, r0 = i2 % 4096;
        int kk = r0 / 2048, r1 = r0 % 2048;
        int nn = r1 / 512,  r2 = r1 % 512;
        int l = r2 / 8,     j = r2 % 8;
        int k = kk * 32 + (l >> 4) * 8 + j;
        int c = nn * 16 + (l & 15);
        w2f[i2] = f2bf(W2[(f * 64 + k) * 64 + c]);
    } else if (idx < 28800) {                // bias1' = b1 + globals @ W1 (full fp32)
        int i3 = idx - 28672; int f = i3 / 64, o = i3 % 64;
        float s = b1[f * 64 + o];
        for (int t = 0; t < 64; ++t) s += h_global[t] * W1[(f * 256 + 128 + t) * 64 + o];
        for (int t = 0; t < 32; ++t) s += enc_global[t] * W1[(f * 256 + 224 + t) * 64 + o];
        bp1[i3] = s;
    } else if (idx < 28928) {
        int i4 = idx - 28800; bp2[i4] = b2[i4];
    } else if (idx < 29056) {
        int i5 = idx - 28928; wp3[i5] = W3[i5];          // W3 is [2][64][1]
    } else if (idx < 29058) {
        bp3[idx - 29056] = b3[idx - 29056];
    }
}

struct Gst {                                 // raw f32 gather state for one 16-edge tile
    float4 f0a, f0b, f1a, f1b, t0a, t0b, t1a, t1b, e0, e1;
    float ea;
};

__device__ inline void gather_tile(int tbase, int n_edges, int n_nodes,
        const int* __restrict__ addr_from, const int* __restrict__ addr_to,
        const float* __restrict__ h_local, const float* __restrict__ enc_local,
        const float* __restrict__ edge_array, int col16, int g, Gst& s) {
    int e = tbase + col16;
    bool ev = e < n_edges;
    int af = ev ? addr_from[e] : -1;
    int at = ev ? addr_to[e] : -1;
    bool afv = (unsigned)af < (unsigned)n_nodes;
    bool atv = (unsigned)at < (unsigned)n_nodes;
    const float* pf = h_local + (size_t)(afv ? af : 0) * 64 + g * 8;
    const float* pt = h_local + (size_t)(atv ? at : 0) * 64 + g * 8;
    s.f0a = ld4(pf, afv);      s.f0b = ld4(pf + 4, afv);
    s.f1a = ld4(pf + 32, afv); s.f1b = ld4(pf + 36, afv);
    s.t0a = ld4(pt, atv);      s.t0b = ld4(pt + 4, atv);
    s.t1a = ld4(pt + 32, atv); s.t1b = ld4(pt + 36, atv);
    const float* pe = enc_local + (size_t)(ev ? e : 0) * 32 + g * 8;
    s.e0 = ld4(pe, ev); s.e1 = ld4(pe + 4, ev);
    s.ea = ev ? edge_array[4 * e] : 0.f;
}

// ---------------- main: 8 waves/block, dynamic chunk (=32 edges) scheduling
template<bool DYN>
__global__ __launch_bounds__(512, 4) void main_kernel(
        const float* __restrict__ edge_array, const float* __restrict__ h_local,
        const float* __restrict__ enc_local,
        const int* __restrict__ addr_from, const int* __restrict__ addr_to,
        char* __restrict__ ws, float* __restrict__ out,
        int n_edges, int n_nodes, int n_chunks) {
    __shared__ __align__(16) char lds[LDS_TOTAL];
    const int tid = threadIdx.x;
    const int lane = tid & 63, wave = tid >> 6;
    const int col16 = lane & 15, g = lane >> 4;
    unsigned* cnt = (unsigned*)(ws + OFF_CNT);

    // grab first chunk + issue its tile-0 gathers BEFORE the staging barrier
    int chunk;
    if (DYN) {
        unsigned id = 0;
        if (lane == 0) id = atomicAdd(cnt, 1u);
        chunk = __shfl((int)id, 0, 64);
    } else {
        chunk = blockIdx.x * NWAVE + wave;
    }
    bool valid = chunk < n_chunks;
    int tb = chunk * 32;
    Gst cur;
    if (valid)
        gather_tile(tb, n_edges, n_nodes, addr_from, addr_to, h_local, enc_local,
                    edge_array, col16, g, cur);

    // stage prepped W block into LDS (linear float4 copy)
    #pragma unroll
    for (int it = 0; it < 7; ++it)
        ((float4*)lds)[it * 512 + tid] = ((const float4*)ws)[it * 512 + tid];
    if (tid < 100)
        ((float4*)(lds + 57344))[tid] = ((const float4*)(ws + 57344))[tid];
    __syncthreads();                                     // ONLY barrier; waves free-run after

    const float* bp1 = (const float*)(lds + OFF_B1);
    const float* bp2 = (const float*)(lds + OFF_B2);
    const float* wp3 = (const float*)(lds + OFF_W3);
    const float* bp3 = (const float*)(lds + OFF_B3);
    short* h1w = (short*)(lds + H1_OFF + wave * 2304);   // [16][72] bf16

    int sub = 0;
    while (valid) {
        // pack cur f32 -> bf16 A-frags (frees the f32 state before next gathers)
        bf16x8 a1[5];
        a1[0] = pack8(cur.f0a, cur.f0b);
        a1[1] = pack8(cur.f1a, cur.f1b);
        a1[2] = pack8(cur.t0a, cur.t0b);
        a1[3] = pack8(cur.t1a, cur.t1b);
        a1[4] = pack8(cur.e0, cur.e1);
        float ea = cur.ea;

        // schedule next tile and issue its gathers (latency hides under MFMAs)
        int tb_next; bool vnext;
        if (sub == 0) {
            tb_next = tb + 16; vnext = tb_next < n_edges; sub = 1;
        } else {
            int c2;
            if (DYN) {
                unsigned id = 0;
                if (lane == 0) id = atomicAdd(cnt, 1u);
                c2 = __shfl((int)id, 0, 64);
            } else {
                c2 = n_chunks;                           // static: one chunk per wave
            }
            vnext = c2 < n_chunks; tb_next = c2 * 32; sub = 0;
        }
        if (vnext)
            gather_tile(tb_next, n_edges, n_nodes, addr_from, addr_to, h_local,
                        enc_local, edge_array, col16, g, cur);

        unsigned long long nanmask = __ballot(__builtin_isnan(ea));

        #pragma unroll
        for (int f = 0; f < 2; ++f) {
            f32x4 zero = {0.f, 0.f, 0.f, 0.f};
            f32x4 acc1[4] = {zero, zero, zero, zero};
            #pragma unroll
            for (int kk = 0; kk < 5; ++kk)
                #pragma unroll
                for (int nn = 0; nn < 4; ++nn) {
                    bf16x8 b = *(const bf16x8*)(lds + OFF_W1 + ((f * 5 + kk) * 4 + nn) * 1024 + lane * 16);
                    acc1[nn] = __builtin_amdgcn_mfma_f32_16x16x32_bf16(a1[kk], b, acc1[nn], 0, 0, 0);
                }

            // bias + leaky_relu, h1 -> LDS (D layout: row=g*4+j (edge), col=col16+16nn)
            #pragma unroll
            for (int nn = 0; nn < 4; ++nn) {
                float bv = bp1[f * 64 + col16 + 16 * nn];
                #pragma unroll
                for (int j = 0; j < 4; ++j) {
                    float v = acc1[nn][j] + bv;
                    v = fmaxf(v, 0.01f * v);
                    h1w[(g * 4 + j) * 72 + col16 + 16 * nn] = f2bf(v);
                }
            }
            asm volatile("s_waitcnt lgkmcnt(0)" ::: "memory");   // wave-internal LDS transpose

            bf16x8 a2[2];                                // layer-2 A frags: row=col16, k=g*8+j
            a2[0] = *(const bf16x8*)((const char*)h1w + col16 * 144 + g * 16);
            a2[1] = *(const bf16x8*)((const char*)h1w + col16 * 144 + 64 + g * 16);

            f32x4 acc2[4] = {zero, zero, zero, zero};
            #pragma unroll
            for (int kk = 0; kk < 2; ++kk)
                #pragma unroll
                for (int nn = 0; nn < 4; ++nn) {
                    bf16x8 b = *(const bf16x8*)(lds + OFF_W2 + ((f * 2 + kk) * 4 + nn) * 1024 + lane * 16);
                    acc2[nn] = __builtin_amdgcn_mfma_f32_16x16x32_bf16(a2[kk], b, acc2[nn], 0, 0, 0);
                }

            // layer 3: per-lane partial dot, reduce across the 16 cols
            float p[4] = {0.f, 0.f, 0.f, 0.f};
            #pragma unroll
            for (int nn = 0; nn < 4; ++nn) {
                float b2v = bp2[f * 64 + col16 + 16 * nn];
                float w3v = wp3[f * 64 + col16 + 16 * nn];
                #pragma unroll
                for (int j = 0; j < 4; ++j) {
                    float h = acc2[nn][j] + b2v;
                    h = fmaxf(h, 0.01f * h);
                    p[j] += h * w3v;
                }
            }
            #pragma unroll
            for (int m = 1; m <= 8; m <<= 1) {
                #pragma unroll
                for (int j = 0; j < 4; ++j) p[j] += __shfl_xor(p[j], m, 64);
            }
            if (col16 == 0) {
                float b3v = bp3[f];
                #pragma unroll
                for (int j = 0; j < 4; ++j) {
                    int ee = tb + g * 4 + j;
                    if (ee < n_edges) {
                        float val = p[j] + b3v;
                        if ((nanmask >> (g * 4 + j)) & 1ull) val = __builtin_nanf("");
                        out[f * n_edges + ee] = val;
                    }
                }
            }
        }

        tb = tb_next; valid = vnext;                     // wave-uniform
    }
}

extern "C" void kernel_launch(void* const* d_in, const int* in_sizes, int n_in,
                              void* d_out, int out_size, void* d_ws, size_t ws_size,
                              hipStream_t stream) {
    const float* edge_array = (const float*)d_in[0];
    const float* h_local    = (const float*)d_in[1];
    const float* h_global   = (const float*)d_in[2];
    const float* enc_local  = (const float*)d_in[3];
    const float* enc_global = (const float*)d_in[4];
    const float* W1 = (const float*)d_in[5];
    const float* b1 = (const float*)d_in[6];
    const float* W2 = (const float*)d_in[7];
    const float* b2 = (const float*)d_in[8];
    const float* W3 = (const float*)d_in[9];
    const float* b3 = (const float*)d_in[10];
    const int* addr_from = (const int*)d_in[11];
    const int* addr_to   = (const int*)d_in[12];
    int n_edges = in_sizes[11];
    int n_nodes = in_sizes[1] / 64;
    char* ws = (char*)d_ws;

    hipLaunchKernelGGL(prep_all, dim3(PREP_W_BLOCKS), dim3(256), 0, stream,
                       W1, b1, W2, b2, W3, b3, h_global, enc_global, ws);

    int n_chunks = (n_edges + 31) / 32;
    bool dyn = ws_size >= (size_t)(OFF_CNT + 4);
    if (dyn) {
        int nblk = 512;                                  // 2 blocks/CU persistent
        if (nblk * NWAVE > n_chunks) nblk = (n_chunks + NWAVE - 1) / NWAVE;
        hipLaunchKernelGGL((main_kernel<true>), dim3(nblk), dim3(512), 0, stream,
                           edge_array, h_local, enc_local, addr_from, addr_to,
                           ws, (float*)d_out, n_edges, n_nodes, n_chunks);
    } else {
        int nblk = (n_chunks + NWAVE - 1) / NWAVE;
        hipLaunchKernelGGL((main_kernel<false>), dim3(nblk), dim3(512), 0, stream,
                           edge_array, h_local, enc_local, addr_from, addr_to,
                           ws, (float*)d_out, n_edges, n_nodes, n_chunks);
    }
}

// Round 5
// 45.730 us; speedup vs baseline: 3.2653x; 3.2653x over previous
//
#include <hip/hip_runtime.h>

// LocalDecoder: per-edge gather + 2 stacked MLPs (256->64->64->1), bf16 MFMA.
//
// ws layout (bytes), produced by prep_all:
//   OFF_W1: bf16 W1frag[2][5][4][64][8]  (f, kk, nn, lane, j)  = 40960
//   OFF_W2: bf16 W2frag[2][2][4][64][8]                        = 16384
//   OFF_B1: f32 bias1p[2][64]  (b1 + h_global/enc_global folded)
//   OFF_B2: f32 b2[2][64];  OFF_W3: f32 w3[2][64];  OFF_B3: f32 b3[2]

#define OFF_W1 0
#define OFF_W2 40960
#define OFF_B1 57344
#define OFF_B2 57856
#define OFF_W3 58368
#define OFF_B3 58880
#define H1_OFF 58944            // per-wave h1 scratch [16][72] bf16 = 2304 B
#define NWAVE 8
#define LDS_TOTAL (H1_OFF + NWAVE * 2304)
#define PREP_W_BLOCKS 114

typedef __attribute__((ext_vector_type(8))) short bf16x8;
typedef __attribute__((ext_vector_type(4))) float f32x4;

__device__ inline short f2bf(float f) {                  // prep-side scalar RNE
    unsigned u = __builtin_bit_cast(unsigned, f);
    u += 0x7FFFu + ((u >> 16) & 1u);
    return (short)(u >> 16);
}

__device__ inline float4 ld4(const float* p, bool v) {
    if (v) return *(const float4*)p;
    return make_float4(0.f, 0.f, 0.f, 0.f);
}

__device__ inline unsigned cvt_pk(float lo, float hi) {  // 2xf32 -> packed 2xbf16 (RNE)
    unsigned r;
    asm("v_cvt_pk_bf16_f32 %0, %1, %2" : "=v"(r) : "v"(lo), "v"(hi));
    return r;
}

__device__ inline bf16x8 pack8(float4 a, float4 b) {     // 4 cvt_pk insts total
    union { bf16x8 v; unsigned u[4]; } r;
    r.u[0] = cvt_pk(a.x, a.y);
    r.u[1] = cvt_pk(a.z, a.w);
    r.u[2] = cvt_pk(b.x, b.y);
    r.u[3] = cvt_pk(b.z, b.w);
    return r.v;
}

// ---------------- prep: W swizzle + bias fold
__global__ void prep_all(const float* __restrict__ W1, const float* __restrict__ b1,
                         const float* __restrict__ W2, const float* __restrict__ b2,
                         const float* __restrict__ W3, const float* __restrict__ b3,
                         const float* __restrict__ h_global, const float* __restrict__ enc_global,
                         char* __restrict__ ws) {
    int idx = blockIdx.x * 256 + threadIdx.x;
    short* w1f = (short*)(ws + OFF_W1);
    short* w2f = (short*)(ws + OFF_W2);
    float* bp1 = (float*)(ws + OFF_B1);
    float* bp2 = (float*)(ws + OFF_B2);
    float* wp3 = (float*)(ws + OFF_W3);
    float* bp3 = (float*)(ws + OFF_B3);
    if (idx < 20480) {                       // W1 fragments, K dims: [gf 0:64 | gt 64:128 | encl 128:160]
        int f = idx / 10240, r0 = idx % 10240;
        int kk = r0 / 2048, r1 = r0 % 2048;
        int nn = r1 / 512,  r2 = r1 % 512;
        int l = r2 / 8,     j = r2 % 8;
        int kt = kk * 32 + (l >> 4) * 8 + j;             // 0..159
        int r = (kt < 128) ? kt : kt + 64;               // enc_local rows live at 192..223
        int c = nn * 16 + (l & 15);
        w1f[idx] = f2bf(W1[(f * 256 + r) * 64 + c]);
    } else if (idx < 28672) {                // W2 fragments
        int i2 = idx - 20480;
        int f = i2 / 4096, r0 = i2 % 4096;
        int kk = r0 / 2048, r1 = r0 % 2048;
        int nn = r1 / 512,  r2 = r1 % 512;
        int l = r2 / 8,     j = r2 % 8;
        int k = kk * 32 + (l >> 4) * 8 + j;
        int c = nn * 16 + (l & 15);
        w2f[i2] = f2bf(W2[(f * 64 + k) * 64 + c]);
    } else if (idx < 28800) {                // bias1' = b1 + globals @ W1 (full fp32)
        int i3 = idx - 28672; int f = i3 / 64, o = i3 % 64;
        float s = b1[f * 64 + o];
        for (int t = 0; t < 64; ++t) s += h_global[t] * W1[(f * 256 + 128 + t) * 64 + o];
        for (int t = 0; t < 32; ++t) s += enc_global[t] * W1[(f * 256 + 224 + t) * 64 + o];
        bp1[i3] = s;
    } else if (idx < 28928) {
        int i4 = idx - 28800; bp2[i4] = b2[i4];
    } else if (idx < 29056) {
        int i5 = idx - 28928; wp3[i5] = W3[i5];          // W3 is [2][64][1]
    } else if (idx < 29058) {
        bp3[idx - 29056] = b3[idx - 29056];
    }
}

struct Tile { bf16x8 a0, a1, a2, a3, a4; float ea; };    // bf16-packed state: 21 VGPRs

__device__ inline void gather_tile(int tbase, int n_edges, int n_nodes,
        const int* __restrict__ addr_from, const int* __restrict__ addr_to,
        const float* __restrict__ h_local, const float* __restrict__ enc_local,
        const float* __restrict__ edge_array, int col16, int g, Tile& T) {
    int e = tbase + col16;
    bool ev = e < n_edges;
    int af = ev ? addr_from[e] : -1;
    int at = ev ? addr_to[e] : -1;
    bool afv = (unsigned)af < (unsigned)n_nodes;
    bool atv = (unsigned)at < (unsigned)n_nodes;
    const float* pf = h_local + (size_t)(afv ? af : 0) * 64 + g * 8;
    const float* pt = h_local + (size_t)(atv ? at : 0) * 64 + g * 8;
    T.a0 = pack8(ld4(pf, afv),      ld4(pf + 4, afv));
    T.a1 = pack8(ld4(pf + 32, afv), ld4(pf + 36, afv));
    T.a2 = pack8(ld4(pt, atv),      ld4(pt + 4, atv));
    T.a3 = pack8(ld4(pt + 32, atv), ld4(pt + 36, atv));
    const float* pe = enc_local + (size_t)(ev ? e : 0) * 32 + g * 8;
    T.a4 = pack8(ld4(pe, ev), ld4(pe + 4, ev));
    T.ea = ev ? edge_array[4 * e] : 0.f;
}

// ---------------- main: persistent 8-wave blocks, wave strides tiles by grid*8
__global__ __launch_bounds__(512, 4) void main_kernel(
        const float* __restrict__ edge_array, const float* __restrict__ h_local,
        const float* __restrict__ enc_local,
        const int* __restrict__ addr_from, const int* __restrict__ addr_to,
        const char* __restrict__ ws, float* __restrict__ out,
        int n_edges, int n_nodes) {
    __shared__ __align__(16) char lds[LDS_TOTAL];
    const int tid = threadIdx.x;
    const int lane = tid & 63, wave = tid >> 6;
    const int col16 = lane & 15, g = lane >> 4;
    const int ntiles = (n_edges + 15) >> 4;
    const int wstride = gridDim.x * NWAVE;

    int t = blockIdx.x * NWAVE + wave;
    bool valid = t < ntiles;
    Tile cur;
    if (valid)                                           // first gather overlaps staging
        gather_tile(t * 16, n_edges, n_nodes, addr_from, addr_to, h_local,
                    enc_local, edge_array, col16, g, cur);

    // stage prepped W block into LDS once per block (linear float4 copy)
    #pragma unroll
    for (int it = 0; it < 7; ++it)
        ((float4*)lds)[it * 512 + tid] = ((const float4*)ws)[it * 512 + tid];
    if (tid < 100)
        ((float4*)(lds + 57344))[tid] = ((const float4*)(ws + 57344))[tid];
    __syncthreads();                                     // only block-wide barrier

    const float* bp1 = (const float*)(lds + OFF_B1);
    const float* bp2 = (const float*)(lds + OFF_B2);
    const float* wp3 = (const float*)(lds + OFF_W3);
    const float* bp3 = (const float*)(lds + OFF_B3);
    unsigned short* h1w = (unsigned short*)(lds + H1_OFF + wave * 2304);  // [16][72]

    while (valid) {
        bf16x8 a1[5] = {cur.a0, cur.a1, cur.a2, cur.a3, cur.a4};
        float ea = cur.ea;
        int tb = t * 16;

        int tn = t + wstride;                            // prefetch next tile (bf16 state)
        bool vnext = tn < ntiles;
        if (vnext)
            gather_tile(tn * 16, n_edges, n_nodes, addr_from, addr_to, h_local,
                        enc_local, edge_array, col16, g, cur);

        unsigned long long nanmask = __ballot(__builtin_isnan(ea));

        #pragma unroll
        for (int f = 0; f < 2; ++f) {
            f32x4 zero = {0.f, 0.f, 0.f, 0.f};
            f32x4 acc1[4] = {zero, zero, zero, zero};
            #pragma unroll
            for (int kk = 0; kk < 5; ++kk)
                #pragma unroll
                for (int nn = 0; nn < 4; ++nn) {
                    bf16x8 b = *(const bf16x8*)(lds + OFF_W1 + ((f * 5 + kk) * 4 + nn) * 1024 + lane * 16);
                    acc1[nn] = __builtin_amdgcn_mfma_f32_16x16x32_bf16(a1[kk], b, acc1[nn], 0, 0, 0);
                }

            // bias + leaky_relu, h1 -> LDS via paired cvt_pk
            // D layout: row=g*4+j (edge), col=col16+16nn; h1 row pitch 72 shorts
            #pragma unroll
            for (int nn = 0; nn < 4; ++nn) {
                float bv = bp1[f * 64 + col16 + 16 * nn];
                float v0 = acc1[nn][0] + bv, v1 = acc1[nn][1] + bv;
                float v2 = acc1[nn][2] + bv, v3 = acc1[nn][3] + bv;
                v0 = fmaxf(v0, 0.01f * v0); v1 = fmaxf(v1, 0.01f * v1);
                v2 = fmaxf(v2, 0.01f * v2); v3 = fmaxf(v3, 0.01f * v3);
                unsigned pk01 = cvt_pk(v0, v1), pk23 = cvt_pk(v2, v3);
                int base = g * 4 * 72 + col16 + 16 * nn;
                h1w[base]       = (unsigned short)pk01;
                h1w[base + 72]  = (unsigned short)(pk01 >> 16);
                h1w[base + 144] = (unsigned short)pk23;
                h1w[base + 216] = (unsigned short)(pk23 >> 16);
            }
            asm volatile("s_waitcnt lgkmcnt(0)" ::: "memory");   // wave-internal LDS transpose

            bf16x8 a2[2];                                // layer-2 A frags: row=col16, k=g*8+j
            a2[0] = *(const bf16x8*)((const char*)h1w + col16 * 144 + g * 16);
            a2[1] = *(const bf16x8*)((const char*)h1w + col16 * 144 + 64 + g * 16);

            f32x4 acc2[4] = {zero, zero, zero, zero};
            #pragma unroll
            for (int kk = 0; kk < 2; ++kk)
                #pragma unroll
                for (int nn = 0; nn < 4; ++nn) {
                    bf16x8 b = *(const bf16x8*)(lds + OFF_W2 + ((f * 2 + kk) * 4 + nn) * 1024 + lane * 16);
                    acc2[nn] = __builtin_amdgcn_mfma_f32_16x16x32_bf16(a2[kk], b, acc2[nn], 0, 0, 0);
                }

            // layer 3: per-lane partial dot, reduce across the 16 cols
            float p[4] = {0.f, 0.f, 0.f, 0.f};
            #pragma unroll
            for (int nn = 0; nn < 4; ++nn) {
                float b2v = bp2[f * 64 + col16 + 16 * nn];
                float w3v = wp3[f * 64 + col16 + 16 * nn];
                #pragma unroll
                for (int j = 0; j < 4; ++j) {
                    float h = acc2[nn][j] + b2v;
                    h = fmaxf(h, 0.01f * h);
                    p[j] += h * w3v;
                }
            }
            #pragma unroll
            for (int m = 1; m <= 8; m <<= 1) {
                #pragma unroll
                for (int j = 0; j < 4; ++j) p[j] += __shfl_xor(p[j], m, 64);
            }
            if (col16 == 0) {
                float b3v = bp3[f];
                #pragma unroll
                for (int j = 0; j < 4; ++j) {
                    int ee = tb + g * 4 + j;
                    if (ee < n_edges) {
                        float val = p[j] + b3v;
                        if ((nanmask >> (g * 4 + j)) & 1ull) val = __builtin_nanf("");
                        out[f * n_edges + ee] = val;
                    }
                }
            }
        }

        t = tn; valid = vnext;                           // wave-uniform
    }
}

extern "C" void kernel_launch(void* const* d_in, const int* in_sizes, int n_in,
                              void* d_out, int out_size, void* d_ws, size_t ws_size,
                              hipStream_t stream) {
    const float* edge_array = (const float*)d_in[0];
    const float* h_local    = (const float*)d_in[1];
    const float* h_global   = (const float*)d_in[2];
    const float* enc_local  = (const float*)d_in[3];
    const float* enc_global = (const float*)d_in[4];
    const float* W1 = (const float*)d_in[5];
    const float* b1 = (const float*)d_in[6];
    const float* W2 = (const float*)d_in[7];
    const float* b2 = (const float*)d_in[8];
    const float* W3 = (const float*)d_in[9];
    const float* b3 = (const float*)d_in[10];
    const int* addr_from = (const int*)d_in[11];
    const int* addr_to   = (const int*)d_in[12];
    int n_edges = in_sizes[11];
    int n_nodes = in_sizes[1] / 64;
    char* ws = (char*)d_ws;

    hipLaunchKernelGGL(prep_all, dim3(PREP_W_BLOCKS), dim3(256), 0, stream,
                       W1, b1, W2, b2, W3, b3, h_global, enc_global, ws);

    int ntiles = (n_edges + 15) / 16;
    int nblk = 512;                                      // 2 persistent blocks/CU
    if (nblk * NWAVE > ntiles) nblk = (ntiles + NWAVE - 1) / NWAVE;
    hipLaunchKernelGGL(main_kernel, dim3(nblk), dim3(512), 0, stream,
                       edge_array, h_local, enc_local, addr_from, addr_to,
                       ws, (float*)d_out, n_edges, n_nodes);
}

// Round 6
// 39.395 us; speedup vs baseline: 3.7904x; 1.1608x over previous
//
#include <hip/hip_runtime.h>

// LocalDecoder: per-edge gather + 2 stacked MLPs (256->64->64->1), bf16 MFMA.
//
// ws layout (bytes):
//   OFF_W1: bf16 W1frag[2][5][4][64][8]  (f, kk, nn, lane, j)  = 40960
//   OFF_W2: bf16 W2frag[2][2][4][64][8]                        = 16384
//   OFF_B1: f32 bias1p[2][64]; OFF_B2: f32 b2[2][64]; OFF_W3: f32 w3[2][64]; OFF_B3: b3
//   off_ea0: f32 ea0[n_edges]         (edge_array[:,0] compacted)
//   off_hbf: bf16 hbf[n_nodes+1][64]  (bf16 h_local; row n_nodes = zeros for fill-0)

#define OFF_W1 0
#define OFF_W2 40960
#define OFF_B1 57344
#define OFF_B2 57856
#define OFF_W3 58368
#define OFF_B3 58880
#define OFF_EA0 59392
#define H1_OFF 58944            // per-wave h1 scratch [16][72] bf16 = 2304 B
#define NWAVE 8
#define LDS_TOTAL (H1_OFF + NWAVE * 2304)
#define PREP_W_BLOCKS 114

typedef __attribute__((ext_vector_type(8))) short bf16x8;
typedef __attribute__((ext_vector_type(4))) float f32x4;

__device__ inline short f2bf(float f) {                  // prep-side scalar RNE
    unsigned u = __builtin_bit_cast(unsigned, f);
    u += 0x7FFFu + ((u >> 16) & 1u);
    return (short)(u >> 16);
}

__device__ inline float4 ld4(const float* p, bool v) {
    if (v) return *(const float4*)p;
    return make_float4(0.f, 0.f, 0.f, 0.f);
}

__device__ inline unsigned cvt_pk(float lo, float hi) {  // 2xf32 -> packed 2xbf16 (RNE)
    unsigned r;
    asm("v_cvt_pk_bf16_f32 %0, %1, %2" : "=v"(r) : "v"(lo), "v"(hi));
    return r;
}

__device__ inline bf16x8 pack8(float4 a, float4 b) {     // 4 cvt_pk insts total
    union { bf16x8 v; unsigned u[4]; } r;
    r.u[0] = cvt_pk(a.x, a.y);
    r.u[1] = cvt_pk(a.z, a.w);
    r.u[2] = cvt_pk(b.x, b.y);
    r.u[3] = cvt_pk(b.z, b.w);
    return r.v;
}

// ---------------- prep: W swizzle + bias fold + ea0 compaction + h_local->bf16
__global__ void prep_all(const float* __restrict__ W1, const float* __restrict__ b1,
                         const float* __restrict__ W2, const float* __restrict__ b2,
                         const float* __restrict__ W3, const float* __restrict__ b3,
                         const float* __restrict__ h_global, const float* __restrict__ enc_global,
                         const float* __restrict__ edge_array, const float* __restrict__ h_local,
                         int n_edges, int n8,
                         float* __restrict__ ea0, short* __restrict__ hbf,
                         char* __restrict__ ws) {
    int b = blockIdx.x;
    if (b >= PREP_W_BLOCKS) {                // streaming conversions
        int rb = b - PREP_W_BLOCKS;
        int eb = (n_edges + 255) >> 8;
        if (rb < eb) {
            int e = rb * 256 + threadIdx.x;
            if (e < n_edges) ea0[e] = ((const float4*)edge_array)[e].x;
        } else {
            int i = (rb - eb) * 256 + threadIdx.x;
            if (i < n8) {
                float4 a = ((const float4*)h_local)[2 * i];
                float4 c = ((const float4*)h_local)[2 * i + 1];
                ((bf16x8*)hbf)[i] = pack8(a, c);
            } else if (i < n8 + 8) {         // zero row (index n_nodes) for fill-0
                ((bf16x8*)hbf)[i] = (bf16x8){0, 0, 0, 0, 0, 0, 0, 0};
            }
        }
        return;
    }
    int idx = b * 256 + threadIdx.x;
    short* w1f = (short*)(ws + OFF_W1);
    short* w2f = (short*)(ws + OFF_W2);
    float* bp1 = (float*)(ws + OFF_B1);
    float* bp2 = (float*)(ws + OFF_B2);
    float* wp3 = (float*)(ws + OFF_W3);
    float* bp3 = (float*)(ws + OFF_B3);
    if (idx < 20480) {                       // W1 fragments, K dims: [gf 0:64 | gt 64:128 | encl 128:160]
        int f = idx / 10240, r0 = idx % 10240;
        int kk = r0 / 2048, r1 = r0 % 2048;
        int nn = r1 / 512,  r2 = r1 % 512;
        int l = r2 / 8,     j = r2 % 8;
        int kt = kk * 32 + (l >> 4) * 8 + j;             // 0..159
        int r = (kt < 128) ? kt : kt + 64;               // enc_local rows live at 192..223
        int c = nn * 16 + (l & 15);
        w1f[idx] = f2bf(W1[(f * 256 + r) * 64 + c]);
    } else if (idx < 28672) {                // W2 fragments
        int i2 = idx - 20480;
        int f = i2 / 4096, r0 = i2 % 4096;
        int kk = r0 / 2048, r1 = r0 % 2048;
        int nn = r1 / 512,  r2 = r1 % 512;
        int l = r2 / 8,     j = r2 % 8;
        int k = kk * 32 + (l >> 4) * 8 + j;
        int c = nn * 16 + (l & 15);
        w2f[i2] = f2bf(W2[(f * 64 + k) * 64 + c]);
    } else if (idx < 28800) {                // bias1' = b1 + globals @ W1 (full fp32)
        int i3 = idx - 28672; int f = i3 / 64, o = i3 % 64;
        float s = b1[f * 64 + o];
        for (int t = 0; t < 64; ++t) s += h_global[t] * W1[(f * 256 + 128 + t) * 64 + o];
        for (int t = 0; t < 32; ++t) s += enc_global[t] * W1[(f * 256 + 224 + t) * 64 + o];
        bp1[i3] = s;
    } else if (idx < 28928) {
        int i4 = idx - 28800; bp2[i4] = b2[i4];
    } else if (idx < 29056) {
        int i5 = idx - 28928; wp3[i5] = W3[i5];          // W3 is [2][64][1]
    } else if (idx < 29058) {
        bp3[idx - 29056] = b3[idx - 29056];
    }
}

// bf16-packed tile state; HBF path = 11 naked loads, ZERO consuming ops
struct Tile { bf16x8 a0, a1, a2, a3; float4 e0, e1; float ea; };

template<bool HBF>
__device__ inline void gather_tile(int tbase, int n_edges, int n_nodes,
        const int* __restrict__ addr_from, const int* __restrict__ addr_to,
        const float* __restrict__ h_local, const short* __restrict__ hbf,
        const float* __restrict__ enc_local, const float* __restrict__ edge_array,
        const float* __restrict__ ea0, int col16, int g, Tile& T) {
    int e = tbase + col16;
    if (HBF) {
        int ec = e < n_edges ? e : n_edges - 1;          // clamp (outputs unwritten)
        int af = addr_from[ec], at = addr_to[ec];
        unsigned ra = (unsigned)af < (unsigned)n_nodes ? (unsigned)af : (unsigned)n_nodes;
        unsigned rt = (unsigned)at < (unsigned)n_nodes ? (unsigned)at : (unsigned)n_nodes;
        const short* pf = hbf + (size_t)ra * 64 + g * 8; // row n_nodes = zeros
        const short* pt = hbf + (size_t)rt * 64 + g * 8;
        T.a0 = *(const bf16x8*)pf; T.a1 = *(const bf16x8*)(pf + 32);
        T.a2 = *(const bf16x8*)pt; T.a3 = *(const bf16x8*)(pt + 32);
        const float* pe = enc_local + (size_t)ec * 32 + g * 8;
        T.e0 = *(const float4*)pe; T.e1 = *(const float4*)(pe + 4);
        T.ea = ea0[ec];
    } else {                                             // fallback (ws too small)
        bool ev = e < n_edges;
        int af = ev ? addr_from[e] : -1;
        int at = ev ? addr_to[e] : -1;
        bool afv = (unsigned)af < (unsigned)n_nodes;
        bool atv = (unsigned)at < (unsigned)n_nodes;
        const float* pf = h_local + (size_t)(afv ? af : 0) * 64 + g * 8;
        const float* pt = h_local + (size_t)(atv ? at : 0) * 64 + g * 8;
        T.a0 = pack8(ld4(pf, afv),      ld4(pf + 4, afv));
        T.a1 = pack8(ld4(pf + 32, afv), ld4(pf + 36, afv));
        T.a2 = pack8(ld4(pt, atv),      ld4(pt + 4, atv));
        T.a3 = pack8(ld4(pt + 32, atv), ld4(pt + 36, atv));
        const float* pe = enc_local + (size_t)(ev ? e : 0) * 32 + g * 8;
        T.e0 = ld4(pe, ev); T.e1 = ld4(pe + 4, ev);
        T.ea = ev ? edge_array[4 * e] : 0.f;
    }
}

// ---------------- main: persistent 8-wave blocks, wave strides tiles by grid*8
template<bool HBF>
__global__ __launch_bounds__(512, 4) void main_kernel(
        const float* __restrict__ edge_array, const float* __restrict__ h_local,
        const float* __restrict__ enc_local,
        const int* __restrict__ addr_from, const int* __restrict__ addr_to,
        const char* __restrict__ ws, const float* __restrict__ ea0,
        const short* __restrict__ hbf, float* __restrict__ out,
        int n_edges, int n_nodes) {
    __shared__ __align__(16) char lds[LDS_TOTAL];
    const int tid = threadIdx.x;
    const int lane = tid & 63, wave = tid >> 6;
    const int col16 = lane & 15, g = lane >> 4;
    const int ntiles = (n_edges + 15) >> 4;
    const int wstride = gridDim.x * NWAVE;

    int t = blockIdx.x * NWAVE + wave;
    bool valid = t < ntiles;
    Tile cur;
    if (valid)                                           // first gather overlaps staging
        gather_tile<HBF>(t * 16, n_edges, n_nodes, addr_from, addr_to, h_local,
                         hbf, enc_local, edge_array, ea0, col16, g, cur);

    // stage prepped W block into LDS once per block (linear float4 copy)
    #pragma unroll
    for (int it = 0; it < 7; ++it)
        ((float4*)lds)[it * 512 + tid] = ((const float4*)ws)[it * 512 + tid];
    if (tid < 100)
        ((float4*)(lds + 57344))[tid] = ((const float4*)(ws + 57344))[tid];
    __syncthreads();                                     // only block-wide barrier

    const float* bp1 = (const float*)(lds + OFF_B1);
    const float* bp2 = (const float*)(lds + OFF_B2);
    const float* wp3 = (const float*)(lds + OFF_W3);
    const float* bp3 = (const float*)(lds + OFF_B3);
    unsigned short* h1w = (unsigned short*)(lds + H1_OFF + wave * 2304);  // [16][72]

    while (valid) {
        // consume tile t (vmcnt waits land HERE, one full compute after issue)
        bf16x8 a1[5] = {cur.a0, cur.a1, cur.a2, cur.a3, pack8(cur.e0, cur.e1)};
        float ea = cur.ea;
        int tb = t * 16;

        int tn = t + wstride;                            // issue tile t+1 loads (no consume)
        bool vnext = tn < ntiles;
        if (vnext)
            gather_tile<HBF>(tn * 16, n_edges, n_nodes, addr_from, addr_to, h_local,
                             hbf, enc_local, edge_array, ea0, col16, g, cur);

        unsigned long long nanmask = __ballot(__builtin_isnan(ea));

        #pragma unroll
        for (int f = 0; f < 2; ++f) {
            f32x4 zero = {0.f, 0.f, 0.f, 0.f};
            f32x4 acc1[4] = {zero, zero, zero, zero};
            #pragma unroll
            for (int kk = 0; kk < 5; ++kk)
                #pragma unroll
                for (int nn = 0; nn < 4; ++nn) {
                    bf16x8 b = *(const bf16x8*)(lds + OFF_W1 + ((f * 5 + kk) * 4 + nn) * 1024 + lane * 16);
                    acc1[nn] = __builtin_amdgcn_mfma_f32_16x16x32_bf16(a1[kk], b, acc1[nn], 0, 0, 0);
                }

            // bias + leaky_relu, h1 -> LDS via paired cvt_pk
            // D layout: row=g*4+j (edge), col=col16+16nn; h1 row pitch 72 shorts
            #pragma unroll
            for (int nn = 0; nn < 4; ++nn) {
                float bv = bp1[f * 64 + col16 + 16 * nn];
                float v0 = acc1[nn][0] + bv, v1 = acc1[nn][1] + bv;
                float v2 = acc1[nn][2] + bv, v3 = acc1[nn][3] + bv;
                v0 = fmaxf(v0, 0.01f * v0); v1 = fmaxf(v1, 0.01f * v1);
                v2 = fmaxf(v2, 0.01f * v2); v3 = fmaxf(v3, 0.01f * v3);
                unsigned pk01 = cvt_pk(v0, v1), pk23 = cvt_pk(v2, v3);
                int base = g * 4 * 72 + col16 + 16 * nn;
                h1w[base]       = (unsigned short)pk01;
                h1w[base + 72]  = (unsigned short)(pk01 >> 16);
                h1w[base + 144] = (unsigned short)pk23;
                h1w[base + 216] = (unsigned short)(pk23 >> 16);
            }
            asm volatile("s_waitcnt lgkmcnt(0)" ::: "memory");   // wave-internal LDS transpose

            bf16x8 a2[2];                                // layer-2 A frags: row=col16, k=g*8+j
            a2[0] = *(const bf16x8*)((const char*)h1w + col16 * 144 + g * 16);
            a2[1] = *(const bf16x8*)((const char*)h1w + col16 * 144 + 64 + g * 16);

            f32x4 acc2[4] = {zero, zero, zero, zero};
            #pragma unroll
            for (int kk = 0; kk < 2; ++kk)
                #pragma unroll
                for (int nn = 0; nn < 4; ++nn) {
                    bf16x8 b = *(const bf16x8*)(lds + OFF_W2 + ((f * 2 + kk) * 4 + nn) * 1024 + lane * 16);
                    acc2[nn] = __builtin_amdgcn_mfma_f32_16x16x32_bf16(a2[kk], b, acc2[nn], 0, 0, 0);
                }

            // layer 3: per-lane partial dot, reduce across the 16 cols
            float p[4] = {0.f, 0.f, 0.f, 0.f};
            #pragma unroll
            for (int nn = 0; nn < 4; ++nn) {
                float b2v = bp2[f * 64 + col16 + 16 * nn];
                float w3v = wp3[f * 64 + col16 + 16 * nn];
                #pragma unroll
                for (int j = 0; j < 4; ++j) {
                    float h = acc2[nn][j] + b2v;
                    h = fmaxf(h, 0.01f * h);
                    p[j] += h * w3v;
                }
            }
            #pragma unroll
            for (int m = 1; m <= 8; m <<= 1) {
                #pragma unroll
                for (int j = 0; j < 4; ++j) p[j] += __shfl_xor(p[j], m, 64);
            }
            if (col16 == 0) {
                float b3v = bp3[f];
                #pragma unroll
                for (int j = 0; j < 4; ++j) {
                    int ee = tb + g * 4 + j;
                    if (ee < n_edges) {
                        float val = p[j] + b3v;
                        if ((nanmask >> (g * 4 + j)) & 1ull) val = __builtin_nanf("");
                        out[f * n_edges + ee] = val;
                    }
                }
            }
        }

        t = tn; valid = vnext;                           // wave-uniform
    }
}

extern "C" void kernel_launch(void* const* d_in, const int* in_sizes, int n_in,
                              void* d_out, int out_size, void* d_ws, size_t ws_size,
                              hipStream_t stream) {
    const float* edge_array = (const float*)d_in[0];
    const float* h_local    = (const float*)d_in[1];
    const float* h_global   = (const float*)d_in[2];
    const float* enc_local  = (const float*)d_in[3];
    const float* enc_global = (const float*)d_in[4];
    const float* W1 = (const float*)d_in[5];
    const float* b1 = (const float*)d_in[6];
    const float* W2 = (const float*)d_in[7];
    const float* b2 = (const float*)d_in[8];
    const float* W3 = (const float*)d_in[9];
    const float* b3 = (const float*)d_in[10];
    const int* addr_from = (const int*)d_in[11];
    const int* addr_to   = (const int*)d_in[12];
    int n_edges = in_sizes[11];
    int n_nodes = in_sizes[1] / 64;
    int n8 = n_nodes * 8;
    char* ws = (char*)d_ws;

    size_t off_ea0 = OFF_EA0;
    size_t off_hbf = (off_ea0 + (size_t)n_edges * 4 + 255) & ~(size_t)255;
    size_t need = off_hbf + (size_t)(n_nodes + 1) * 128;
    bool use_hbf = ws_size >= need;
    float* ea0 = (float*)(ws + off_ea0);
    short* hbf = (short*)(ws + off_hbf);

    int eb = (n_edges + 255) / 256;
    int hb = (n8 + 8 + 255) / 256;
    int prep_blocks = PREP_W_BLOCKS + (use_hbf ? eb + hb : 0);
    hipLaunchKernelGGL(prep_all, dim3(prep_blocks), dim3(256), 0, stream,
                       W1, b1, W2, b2, W3, b3, h_global, enc_global,
                       edge_array, h_local, n_edges, n8, ea0, hbf, ws);

    int ntiles = (n_edges + 15) / 16;
    int nblk = 512;                                      // 2 persistent blocks/CU
    if (nblk * NWAVE > ntiles) nblk = (ntiles + NWAVE - 1) / NWAVE;
    if (use_hbf) {
        hipLaunchKernelGGL((main_kernel<true>), dim3(nblk), dim3(512), 0, stream,
                           edge_array, h_local, enc_local, addr_from, addr_to,
                           ws, ea0, hbf, (float*)d_out, n_edges, n_nodes);
    } else {
        hipLaunchKernelGGL((main_kernel<false>), dim3(nblk), dim3(512), 0, stream,
                           edge_array, h_local, enc_local, addr_from, addr_to,
                           ws, ea0, hbf, (float*)d_out, n_edges, n_nodes);
    }
}

// Round 7
// 37.244 us; speedup vs baseline: 4.0093x; 1.0577x over previous
//
#include <hip/hip_runtime.h>

// LocalDecoder: per-edge gather + 2 stacked MLPs (256->64->64->1), bf16 MFMA.
// Swapped-operand design: MFMA A = weight frag, B = x frag -> D[out][edge],
// edge = lane&15. Bias = f32x4 acc-init, h1 redistribution via ds_bpermute
// (no LDS round trip, no lgkmcnt drains), layer-3 reduce = 2 shfl_xor,
// coalesced 16-lane stores.
//
// ws layout (bytes):
//   OFF_W1: bf16 W1frag[2][5][4][64][8]  (f, kk, mm, lane, j)  = 40960
//   OFF_W2: bf16 W2frag[2][2][4][64][8]                        = 16384
//   OFF_B1: f32 bias1p[2][64]; OFF_B2: f32 b2[2][64]; OFF_W3: f32 w3[2][64]; OFF_B3: b3
//   off_ea0: f32 ea0[n_edges]         (edge_array[:,0] compacted)
//   off_hbf: bf16 hbf[n_nodes+1][64]  (bf16 h_local; row n_nodes = zeros for fill-0)

#define OFF_W1 0
#define OFF_W2 40960
#define OFF_B1 57344
#define OFF_B2 57856
#define OFF_W3 58368
#define OFF_B3 58880
#define OFF_EA0 59392
#define NWAVE 8
#define LDS_TOTAL 58944
#define PREP_W_BLOCKS 114

typedef __attribute__((ext_vector_type(8))) short bf16x8;
typedef __attribute__((ext_vector_type(4))) float f32x4;

__device__ inline short f2bf(float f) {                  // prep-side scalar RNE
    unsigned u = __builtin_bit_cast(unsigned, f);
    u += 0x7FFFu + ((u >> 16) & 1u);
    return (short)(u >> 16);
}

__device__ inline float4 ld4(const float* p, bool v) {
    if (v) return *(const float4*)p;
    return make_float4(0.f, 0.f, 0.f, 0.f);
}

__device__ inline unsigned cvt_pk(float lo, float hi) {  // 2xf32 -> packed 2xbf16 (RNE)
    unsigned r;
    asm("v_cvt_pk_bf16_f32 %0, %1, %2" : "=v"(r) : "v"(lo), "v"(hi));
    return r;
}

__device__ inline bf16x8 pack8(float4 a, float4 b) {
    union { bf16x8 v; unsigned u[4]; } r;
    r.u[0] = cvt_pk(a.x, a.y);
    r.u[1] = cvt_pk(a.z, a.w);
    r.u[2] = cvt_pk(b.x, b.y);
    r.u[3] = cvt_pk(b.z, b.w);
    return r.v;
}

// ---------------- prep: W swizzle + bias fold + ea0 compaction + h_local->bf16
// (fragment tables unchanged: A/B layouts are symmetric, same table serves both)
__global__ void prep_all(const float* __restrict__ W1, const float* __restrict__ b1,
                         const float* __restrict__ W2, const float* __restrict__ b2,
                         const float* __restrict__ W3, const float* __restrict__ b3,
                         const float* __restrict__ h_global, const float* __restrict__ enc_global,
                         const float* __restrict__ edge_array, const float* __restrict__ h_local,
                         int n_edges, int n8,
                         float* __restrict__ ea0, short* __restrict__ hbf,
                         char* __restrict__ ws) {
    int b = blockIdx.x;
    if (b >= PREP_W_BLOCKS) {                // streaming conversions
        int rb = b - PREP_W_BLOCKS;
        int eb = (n_edges + 255) >> 8;
        if (rb < eb) {
            int e = rb * 256 + threadIdx.x;
            if (e < n_edges) ea0[e] = ((const float4*)edge_array)[e].x;
        } else {
            int i = (rb - eb) * 256 + threadIdx.x;
            if (i < n8) {
                float4 a = ((const float4*)h_local)[2 * i];
                float4 c = ((const float4*)h_local)[2 * i + 1];
                ((bf16x8*)hbf)[i] = pack8(a, c);
            } else if (i < n8 + 8) {         // zero row (index n_nodes) for fill-0
                ((bf16x8*)hbf)[i] = (bf16x8){0, 0, 0, 0, 0, 0, 0, 0};
            }
        }
        return;
    }
    int idx = b * 256 + threadIdx.x;
    short* w1f = (short*)(ws + OFF_W1);
    short* w2f = (short*)(ws + OFF_W2);
    float* bp1 = (float*)(ws + OFF_B1);
    float* bp2 = (float*)(ws + OFF_B2);
    float* wp3 = (float*)(ws + OFF_W3);
    float* bp3 = (float*)(ws + OFF_B3);
    if (idx < 20480) {                       // W1 fragments, K dims: [gf 0:64 | gt 64:128 | encl 128:160]
        int f = idx / 10240, r0 = idx % 10240;
        int kk = r0 / 2048, r1 = r0 % 2048;
        int mm = r1 / 512,  r2 = r1 % 512;
        int l = r2 / 8,     j = r2 % 8;
        int kt = kk * 32 + (l >> 4) * 8 + j;             // 0..159
        int r = (kt < 128) ? kt : kt + 64;               // enc_local rows live at 192..223
        int c = mm * 16 + (l & 15);
        w1f[idx] = f2bf(W1[(f * 256 + r) * 64 + c]);
    } else if (idx < 28672) {                // W2 fragments
        int i2 = idx - 20480;
        int f = i2 / 4096, r0 = i2 % 4096;
        int kk = r0 / 2048, r1 = r0 % 2048;
        int mm = r1 / 512,  r2 = r1 % 512;
        int l = r2 / 8,     j = r2 % 8;
        int k = kk * 32 + (l >> 4) * 8 + j;
        int c = mm * 16 + (l & 15);
        w2f[i2] = f2bf(W2[(f * 64 + k) * 64 + c]);
    } else if (idx < 28800) {                // bias1' = b1 + globals @ W1 (full fp32)
        int i3 = idx - 28672; int f = i3 / 64, o = i3 % 64;
        float s = b1[f * 64 + o];
        for (int t = 0; t < 64; ++t) s += h_global[t] * W1[(f * 256 + 128 + t) * 64 + o];
        for (int t = 0; t < 32; ++t) s += enc_global[t] * W1[(f * 256 + 224 + t) * 64 + o];
        bp1[i3] = s;
    } else if (idx < 28928) {
        int i4 = idx - 28800; bp2[i4] = b2[i4];
    } else if (idx < 29056) {
        int i5 = idx - 28928; wp3[i5] = W3[i5];          // W3 is [2][64][1]
    } else if (idx < 29058) {
        bp3[idx - 29056] = b3[idx - 29056];
    }
}

// bf16-packed tile state; HBF path = 11 naked loads, ZERO consuming ops
struct Tile { bf16x8 a0, a1, a2, a3; float4 e0, e1; float ea; };

template<bool HBF>
__device__ inline void gather_tile(int tbase, int n_edges, int n_nodes,
        const int* __restrict__ addr_from, const int* __restrict__ addr_to,
        const float* __restrict__ h_local, const short* __restrict__ hbf,
        const float* __restrict__ enc_local, const float* __restrict__ edge_array,
        const float* __restrict__ ea0, int col16, int g, Tile& T) {
    int e = tbase + col16;
    if (HBF) {
        int ec = e < n_edges ? e : n_edges - 1;          // clamp (outputs unwritten)
        int af = addr_from[ec], at = addr_to[ec];
        unsigned ra = (unsigned)af < (unsigned)n_nodes ? (unsigned)af : (unsigned)n_nodes;
        unsigned rt = (unsigned)at < (unsigned)n_nodes ? (unsigned)at : (unsigned)n_nodes;
        const short* pf = hbf + (size_t)ra * 64 + g * 8; // row n_nodes = zeros
        const short* pt = hbf + (size_t)rt * 64 + g * 8;
        T.a0 = *(const bf16x8*)pf; T.a1 = *(const bf16x8*)(pf + 32);
        T.a2 = *(const bf16x8*)pt; T.a3 = *(const bf16x8*)(pt + 32);
        const float* pe = enc_local + (size_t)ec * 32 + g * 8;
        T.e0 = *(const float4*)pe; T.e1 = *(const float4*)(pe + 4);
        T.ea = ea0[ec];
    } else {                                             // fallback (ws too small)
        bool ev = e < n_edges;
        int af = ev ? addr_from[e] : -1;
        int at = ev ? addr_to[e] : -1;
        bool afv = (unsigned)af < (unsigned)n_nodes;
        bool atv = (unsigned)at < (unsigned)n_nodes;
        const float* pf = h_local + (size_t)(afv ? af : 0) * 64 + g * 8;
        const float* pt = h_local + (size_t)(atv ? at : 0) * 64 + g * 8;
        T.a0 = pack8(ld4(pf, afv),      ld4(pf + 4, afv));
        T.a1 = pack8(ld4(pf + 32, afv), ld4(pf + 36, afv));
        T.a2 = pack8(ld4(pt, atv),      ld4(pt + 4, atv));
        T.a3 = pack8(ld4(pt + 32, atv), ld4(pt + 36, atv));
        const float* pe = enc_local + (size_t)(ev ? e : 0) * 32 + g * 8;
        T.e0 = ld4(pe, ev); T.e1 = ld4(pe + 4, ev);
        T.ea = ev ? edge_array[4 * e] : 0.f;
    }
}

// ---------------- main: persistent 8-wave blocks, wave strides tiles by grid*8
template<bool HBF>
__global__ __launch_bounds__(512, 4) void main_kernel(
        const float* __restrict__ edge_array, const float* __restrict__ h_local,
        const float* __restrict__ enc_local,
        const int* __restrict__ addr_from, const int* __restrict__ addr_to,
        const char* __restrict__ ws, const float* __restrict__ ea0,
        const short* __restrict__ hbf, float* __restrict__ out,
        int n_edges, int n_nodes) {
    __shared__ __align__(16) char lds[LDS_TOTAL];
    const int tid = threadIdx.x;
    const int lane = tid & 63, wave = tid >> 6;
    const int col16 = lane & 15, g = lane >> 4;
    const int g4 = g * 4;
    const bool hi = g >= 2;                              // selects mm-high source
    const int srcA = col16 + 32 * (g & 1);               // bpermute src lanes
    const int srcB = srcA + 16;
    const int ntiles = (n_edges + 15) >> 4;
    const int wstride = gridDim.x * NWAVE;

    int t = blockIdx.x * NWAVE + wave;
    bool valid = t < ntiles;
    Tile cur;
    if (valid)                                           // first gather overlaps staging
        gather_tile<HBF>(t * 16, n_edges, n_nodes, addr_from, addr_to, h_local,
                         hbf, enc_local, edge_array, ea0, col16, g, cur);

    // stage prepped W block into LDS once per block (linear float4 copy)
    #pragma unroll
    for (int it = 0; it < 7; ++it)
        ((float4*)lds)[it * 512 + tid] = ((const float4*)ws)[it * 512 + tid];
    if (tid < 100)
        ((float4*)(lds + 57344))[tid] = ((const float4*)(ws + 57344))[tid];
    __syncthreads();                                     // only block-wide barrier

    const float b3v0 = ((const float*)(lds + OFF_B3))[0];
    const float b3v1 = ((const float*)(lds + OFF_B3))[1];

    while (valid) {
        // consume tile t (vmcnt waits land HERE, one full compute after issue)
        bf16x8 a1[5] = {cur.a0, cur.a1, cur.a2, cur.a3, pack8(cur.e0, cur.e1)};
        float ea = cur.ea;
        int tb = t * 16;

        int tn = t + wstride;                            // issue tile t+1 loads (no consume)
        bool vnext = tn < ntiles;
        if (vnext)
            gather_tile<HBF>(tn * 16, n_edges, n_nodes, addr_from, addr_to, h_local,
                             hbf, enc_local, edge_array, ea0, col16, g, cur);

        #pragma unroll
        for (int f = 0; f < 2; ++f) {
            // ---- layer 1: D1[o][e], o = 16mm + 4g + jj, e = col16
            f32x4 acc1[4];
            #pragma unroll
            for (int mm = 0; mm < 4; ++mm)               // bias as acc-init (f32x4)
                acc1[mm] = *(const f32x4*)(lds + OFF_B1 + (f * 64 + mm * 16 + g4) * 4);
            #pragma unroll
            for (int kk = 0; kk < 5; ++kk)
                #pragma unroll
                for (int mm = 0; mm < 4; ++mm) {
                    bf16x8 w = *(const bf16x8*)(lds + OFF_W1 + ((f * 5 + kk) * 4 + mm) * 1024 + lane * 16);
                    acc1[mm] = __builtin_amdgcn_mfma_f32_16x16x32_bf16(w, a1[kk], acc1[mm], 0, 0, 0);
                }

            // lrelu + pack: pk[mm][p] = bf16 pair (o = 16mm+4g+2p, +1)
            unsigned pk[4][2];
            #pragma unroll
            for (int mm = 0; mm < 4; ++mm) {
                float v0 = acc1[mm][0], v1 = acc1[mm][1];
                float v2 = acc1[mm][2], v3 = acc1[mm][3];
                v0 = fmaxf(v0, 0.01f * v0); v1 = fmaxf(v1, 0.01f * v1);
                v2 = fmaxf(v2, 0.01f * v2); v3 = fmaxf(v3, 0.01f * v3);
                pk[mm][0] = cvt_pk(v0, v1);
                pk[mm][1] = cvt_pk(v2, v3);
            }

            // ---- layer 2: in-register redistribution (ds_bpermute), no LDS h1
            f32x4 acc2[4];
            #pragma unroll
            for (int mm = 0; mm < 4; ++mm)               // b2 as acc-init
                acc2[mm] = *(const f32x4*)(lds + OFF_B2 + (f * 64 + mm * 16 + g4) * 4);
            #pragma unroll
            for (int kk2 = 0; kk2 < 2; ++kk2) {
                unsigned mL0 = pk[2 * kk2][0],     mL1 = pk[2 * kk2][1];
                unsigned mH0 = pk[2 * kk2 + 1][0], mH1 = pk[2 * kk2 + 1][1];
                unsigned t0L = (unsigned)__shfl((int)mL0, srcA, 64);
                unsigned t0H = (unsigned)__shfl((int)mH0, srcA, 64);
                unsigned t1L = (unsigned)__shfl((int)mL1, srcA, 64);
                unsigned t1H = (unsigned)__shfl((int)mH1, srcA, 64);
                unsigned t2L = (unsigned)__shfl((int)mL0, srcB, 64);
                unsigned t2H = (unsigned)__shfl((int)mH0, srcB, 64);
                unsigned t3L = (unsigned)__shfl((int)mL1, srcB, 64);
                unsigned t3H = (unsigned)__shfl((int)mH1, srcB, 64);
                union { bf16x8 v; unsigned u[4]; } bb;
                bb.u[0] = hi ? t0H : t0L;                // B2[k2 = 32kk2 + 8g + j][e=c]
                bb.u[1] = hi ? t1H : t1L;
                bb.u[2] = hi ? t2H : t2L;
                bb.u[3] = hi ? t3H : t3L;
                #pragma unroll
                for (int mm = 0; mm < 4; ++mm) {
                    bf16x8 w = *(const bf16x8*)(lds + OFF_W2 + ((f * 2 + kk2) * 4 + mm) * 1024 + lane * 16);
                    acc2[mm] = __builtin_amdgcn_mfma_f32_16x16x32_bf16(w, bb.v, acc2[mm], 0, 0, 0);
                }
            }

            // ---- layer 3: per-lane 16-elem dot, 2-step cross-g reduce
            float p = 0.f;
            #pragma unroll
            for (int mm = 0; mm < 4; ++mm) {
                f32x4 wv = *(const f32x4*)(lds + OFF_W3 + (f * 64 + mm * 16 + g4) * 4);
                #pragma unroll
                for (int jj = 0; jj < 4; ++jj) {
                    float h = acc2[mm][jj];
                    h = fmaxf(h, 0.01f * h);
                    p = fmaf(h, wv[jj], p);
                }
            }
            p += __shfl_xor(p, 16, 64);
            p += __shfl_xor(p, 32, 64);
            if (lane < 16) {                             // coalesced 16-lane store
                int ee = tb + lane;
                if (ee < n_edges) {
                    float val = p + (f == 0 ? b3v0 : b3v1);
                    if (__builtin_isnan(ea)) val = __builtin_nanf("");
                    out[f * n_edges + ee] = val;
                }
            }
        }

        t = tn; valid = vnext;                           // wave-uniform
    }
}

extern "C" void kernel_launch(void* const* d_in, const int* in_sizes, int n_in,
                              void* d_out, int out_size, void* d_ws, size_t ws_size,
                              hipStream_t stream) {
    const float* edge_array = (const float*)d_in[0];
    const float* h_local    = (const float*)d_in[1];
    const float* h_global   = (const float*)d_in[2];
    const float* enc_local  = (const float*)d_in[3];
    const float* enc_global = (const float*)d_in[4];
    const float* W1 = (const float*)d_in[5];
    const float* b1 = (const float*)d_in[6];
    const float* W2 = (const float*)d_in[7];
    const float* b2 = (const float*)d_in[8];
    const float* W3 = (const float*)d_in[9];
    const float* b3 = (const float*)d_in[10];
    const int* addr_from = (const int*)d_in[11];
    const int* addr_to   = (const int*)d_in[12];
    int n_edges = in_sizes[11];
    int n_nodes = in_sizes[1] / 64;
    int n8 = n_nodes * 8;
    char* ws = (char*)d_ws;

    size_t off_ea0 = OFF_EA0;
    size_t off_hbf = (off_ea0 + (size_t)n_edges * 4 + 255) & ~(size_t)255;
    size_t need = off_hbf + (size_t)(n_nodes + 1) * 128;
    bool use_hbf = ws_size >= need;
    float* ea0 = (float*)(ws + off_ea0);
    short* hbf = (short*)(ws + off_hbf);

    int eb = (n_edges + 255) / 256;
    int hb = (n8 + 8 + 255) / 256;
    int prep_blocks = PREP_W_BLOCKS + (use_hbf ? eb + hb : 0);
    hipLaunchKernelGGL(prep_all, dim3(prep_blocks), dim3(256), 0, stream,
                       W1, b1, W2, b2, W3, b3, h_global, enc_global,
                       edge_array, h_local, n_edges, n8, ea0, hbf, ws);

    int ntiles = (n_edges + 15) / 16;
    int nblk = 512;                                      // 2 persistent blocks/CU
    if (nblk * NWAVE > ntiles) nblk = (ntiles + NWAVE - 1) / NWAVE;
    if (use_hbf) {
        hipLaunchKernelGGL((main_kernel<true>), dim3(nblk), dim3(512), 0, stream,
                           edge_array, h_local, enc_local, addr_from, addr_to,
                           ws, ea0, hbf, (float*)d_out, n_edges, n_nodes);
    } else {
        hipLaunchKernelGGL((main_kernel<false>), dim3(nblk), dim3(512), 0, stream,
                           edge_array, h_local, enc_local, addr_from, addr_to,
                           ws, ea0, hbf, (float*)d_out, n_edges, n_nodes);
    }
}

// Round 8
// 35.750 us; speedup vs baseline: 4.1769x; 1.0418x over previous
//
#include <hip/hip_runtime.h>

// LocalDecoder: per-edge gather + 2 stacked MLPs (256->64->64->1).
// 32x32x16 MFMA, edges on N=32: A = weight frag (M=out), B = x frag (N=edge).
// D layout (m74): col=lane&31 (edge), row=(reg&3)+8*(reg>>2)+4*(lane>>5).
// Layer1->2 redistribution: lane-pair (l, l^32) exchange via shfl_xor(32).
//
// ws layout (bytes):
//   OFF_W1: bf16 W1frag[2][10][2][64][8]  (f, kk, mm, lane, j) = 40960
//   OFF_W2: bf16 W2frag[2][4][2][64][8]                        = 16384
//   OFF_B1: f32 bias1p[2][64]; OFF_B2: f32 b2[2][64]; OFF_W3: f32 w3[2][64]; OFF_B3: b3
//   off_ea0: f32 ea0[n_edges];  off_hbf: bf16 hbf[n_nodes+1][64] (row n_nodes = 0)

#define OFF_W1 0
#define OFF_W2 40960
#define OFF_B1 57344
#define OFF_B2 57856
#define OFF_W3 58368
#define OFF_B3 58880
#define OFF_EA0 59392
#define NWAVE 8
#define LDS_TOTAL 58944
#define PREP_W_BLOCKS 114

typedef __attribute__((ext_vector_type(8))) short bf16x8;
typedef __attribute__((ext_vector_type(4))) float f32x4;
typedef __attribute__((ext_vector_type(16))) float f32x16;

__device__ inline short f2bf(float f) {                  // prep-side scalar RNE
    unsigned u = __builtin_bit_cast(unsigned, f);
    u += 0x7FFFu + ((u >> 16) & 1u);
    return (short)(u >> 16);
}

__device__ inline float4 ld4(const float* p, bool v) {
    if (v) return *(const float4*)p;
    return make_float4(0.f, 0.f, 0.f, 0.f);
}

__device__ inline unsigned cvt_pk(float lo, float hi) {  // 2xf32 -> packed 2xbf16 (RNE)
    unsigned r;
    asm("v_cvt_pk_bf16_f32 %0, %1, %2" : "=v"(r) : "v"(lo), "v"(hi));
    return r;
}

__device__ inline bf16x8 pack8(float4 a, float4 b) {
    union { bf16x8 v; unsigned u[4]; } r;
    r.u[0] = cvt_pk(a.x, a.y);
    r.u[1] = cvt_pk(a.z, a.w);
    r.u[2] = cvt_pk(b.x, b.y);
    r.u[3] = cvt_pk(b.z, b.w);
    return r.v;
}

__device__ inline float lrelu(float x) { return fmaxf(x, 0.01f * x); }

// ---------------- prep: W swizzle (32x32 frag layout) + bias fold + ea0 + hbf
__global__ void prep_all(const float* __restrict__ W1, const float* __restrict__ b1,
                         const float* __restrict__ W2, const float* __restrict__ b2,
                         const float* __restrict__ W3, const float* __restrict__ b3,
                         const float* __restrict__ h_global, const float* __restrict__ enc_global,
                         const float* __restrict__ edge_array, const float* __restrict__ h_local,
                         int n_edges, int n8,
                         float* __restrict__ ea0, short* __restrict__ hbf,
                         char* __restrict__ ws) {
    int b = blockIdx.x;
    if (b >= PREP_W_BLOCKS) {                // streaming conversions
        int rb = b - PREP_W_BLOCKS;
        int eb = (n_edges + 255) >> 8;
        if (rb < eb) {
            int e = rb * 256 + threadIdx.x;
            if (e < n_edges) ea0[e] = ((const float4*)edge_array)[e].x;
        } else {
            int i = (rb - eb) * 256 + threadIdx.x;
            if (i < n8) {
                float4 a = ((const float4*)h_local)[2 * i];
                float4 c = ((const float4*)h_local)[2 * i + 1];
                ((bf16x8*)hbf)[i] = pack8(a, c);
            } else if (i < n8 + 8) {         // zero row (index n_nodes) for fill-0
                ((bf16x8*)hbf)[i] = (bf16x8){0, 0, 0, 0, 0, 0, 0, 0};
            }
        }
        return;
    }
    int idx = b * 256 + threadIdx.x;
    short* w1f = (short*)(ws + OFF_W1);
    short* w2f = (short*)(ws + OFF_W2);
    float* bp1 = (float*)(ws + OFF_B1);
    float* bp2 = (float*)(ws + OFF_B2);
    float* wp3 = (float*)(ws + OFF_W3);
    float* bp3 = (float*)(ws + OFF_B3);
    if (idx < 20480) {                       // W1 frags: A row=out=32mm+(l&31), k=16kk+8(l>>5)+j
        int f = idx / 10240, r0 = idx % 10240;
        int kk = r0 / 1024, r1 = r0 % 1024;
        int mm = r1 / 512,  r2 = r1 % 512;
        int l = r2 / 8,     j = r2 % 8;
        int kt = kk * 16 + (l >> 5) * 8 + j;             // 0..159
        int r = (kt < 128) ? kt : kt + 64;               // enc_local rows live at 192..223
        int c = mm * 32 + (l & 31);
        w1f[idx] = f2bf(W1[(f * 256 + r) * 64 + c]);
    } else if (idx < 28672) {                // W2 frags
        int i2 = idx - 20480;
        int f = i2 / 4096, r0 = i2 % 4096;
        int kk2 = r0 / 1024, r1 = r0 % 1024;
        int mm = r1 / 512,  r2 = r1 % 512;
        int l = r2 / 8,     j = r2 % 8;
        int k = kk2 * 16 + (l >> 5) * 8 + j;
        int c = mm * 32 + (l & 31);
        w2f[i2] = f2bf(W2[(f * 64 + k) * 64 + c]);
    } else if (idx < 28800) {                // bias1' = b1 + globals @ W1 (full fp32)
        int i3 = idx - 28672; int f = i3 / 64, o = i3 % 64;
        float s = b1[f * 64 + o];
        for (int t = 0; t < 64; ++t) s += h_global[t] * W1[(f * 256 + 128 + t) * 64 + o];
        for (int t = 0; t < 32; ++t) s += enc_global[t] * W1[(f * 256 + 224 + t) * 64 + o];
        bp1[i3] = s;
    } else if (idx < 28928) {
        int i4 = idx - 28800; bp2[i4] = b2[i4];
    } else if (idx < 29056) {
        int i5 = idx - 28928; wp3[i5] = W3[i5];          // W3 is [2][64][1]
    } else if (idx < 29058) {
        bp3[idx - 29056] = b3[idx - 29056];
    }
}

// ---------------- main: persistent 8-wave blocks; 32 edges per wave-iteration
template<bool HBF>
__global__ __launch_bounds__(512, 4) void main_kernel(
        const float* __restrict__ h_local, const float* __restrict__ enc_local,
        const int* __restrict__ addr_from, const int* __restrict__ addr_to,
        const char* __restrict__ ws, const float* __restrict__ ea0,
        const short* __restrict__ hbf, float* __restrict__ out,
        int n_edges, int n_nodes) {
    __shared__ __align__(16) char lds[LDS_TOTAL];
    const int tid = threadIdx.x;
    const int lane = tid & 63, wave = tid >> 6;
    const int col = lane & 31, hi = lane >> 5;
    const int niters = (n_edges + 31) >> 5;
    const int stride = gridDim.x * NWAVE;

    int t = blockIdx.x * NWAVE + wave;
    bool valid = t < niters;
    int af = 0, at = 0;
    if (valid) {                                         // index prefetch (breaks addr->node chain)
        int ec0 = t * 32 + col; if (ec0 >= n_edges) ec0 = n_edges - 1;
        af = addr_from[ec0]; at = addr_to[ec0];
    }

    // stage prepped W block into LDS once per block (linear float4 copy)
    #pragma unroll
    for (int it = 0; it < 7; ++it)
        ((float4*)lds)[it * 512 + tid] = ((const float4*)ws)[it * 512 + tid];
    if (tid < 100)
        ((float4*)(lds + 57344))[tid] = ((const float4*)(ws + 57344))[tid];
    __syncthreads();                                     // only block-wide barrier

    const float b3v0 = ((const float*)(lds + OFF_B3))[0];
    const float b3v1 = ((const float*)(lds + OFF_B3))[1];

    while (valid) {
        int tb = t * 32;
        int ec = tb + col; if (ec >= n_edges) ec = n_edges - 1;

        // ---- gather: 13 naked loads (HBF), k = 16kk + 8hi + j
        bf16x8 a1[10];
        float4 e0, e1, e2, e3;
        float ea;
        if (HBF) {
            unsigned ra = (unsigned)af < (unsigned)n_nodes ? (unsigned)af : (unsigned)n_nodes;
            unsigned rt = (unsigned)at < (unsigned)n_nodes ? (unsigned)at : (unsigned)n_nodes;
            const short* pf = hbf + (size_t)ra * 64 + hi * 8;
            const short* pt = hbf + (size_t)rt * 64 + hi * 8;
            a1[0] = *(const bf16x8*)pf;        a1[1] = *(const bf16x8*)(pf + 16);
            a1[2] = *(const bf16x8*)(pf + 32); a1[3] = *(const bf16x8*)(pf + 48);
            a1[4] = *(const bf16x8*)pt;        a1[5] = *(const bf16x8*)(pt + 16);
            a1[6] = *(const bf16x8*)(pt + 32); a1[7] = *(const bf16x8*)(pt + 48);
            const float* pe = enc_local + (size_t)ec * 32 + hi * 8;
            e0 = *(const float4*)pe;        e1 = *(const float4*)(pe + 4);
            e2 = *(const float4*)(pe + 16); e3 = *(const float4*)(pe + 20);
            ea = ea0[ec];
        } else {
            bool afv = (unsigned)af < (unsigned)n_nodes;
            bool atv = (unsigned)at < (unsigned)n_nodes;
            const float* pf = h_local + (size_t)(afv ? af : 0) * 64 + hi * 8;
            const float* pt = h_local + (size_t)(atv ? at : 0) * 64 + hi * 8;
            #pragma unroll
            for (int kk = 0; kk < 4; ++kk) {
                a1[kk]     = pack8(ld4(pf + 16 * kk, afv), ld4(pf + 16 * kk + 4, afv));
                a1[kk + 4] = pack8(ld4(pt + 16 * kk, atv), ld4(pt + 16 * kk + 4, atv));
            }
            const float* pe = enc_local + (size_t)ec * 32 + hi * 8;
            e0 = *(const float4*)pe;        e1 = *(const float4*)(pe + 4);
            e2 = *(const float4*)(pe + 16); e3 = *(const float4*)(pe + 20);
            ea = ea0[ec];
        }

        // prefetch NEXT iteration's indices (latency hides under this tile's MFMAs)
        int tn = t + stride;
        bool vnext = tn < niters;
        int af2 = 0, at2 = 0;
        if (vnext) {
            int ec2 = tn * 32 + col; if (ec2 >= n_edges) ec2 = n_edges - 1;
            af2 = addr_from[ec2]; at2 = addr_to[ec2];
        }

        a1[8] = pack8(e0, e1);                           // enc -> bf16 frags (kk 8,9)
        a1[9] = pack8(e2, e3);

        #pragma unroll
        for (int f = 0; f < 2; ++f) {
            // ---- layer 1: D[out][edge]; bias as C-init
            f32x16 acc[2];
            #pragma unroll
            for (int mm = 0; mm < 2; ++mm)
                #pragma unroll
                for (int q2 = 0; q2 < 4; ++q2) {
                    f32x4 v = *(const f32x4*)(lds + OFF_B1 + (f * 64 + mm * 32 + q2 * 8 + hi * 4) * 4);
                    acc[mm][q2 * 4 + 0] = v[0]; acc[mm][q2 * 4 + 1] = v[1];
                    acc[mm][q2 * 4 + 2] = v[2]; acc[mm][q2 * 4 + 3] = v[3];
                }
            #pragma unroll
            for (int kk = 0; kk < 10; ++kk)
                #pragma unroll
                for (int mm = 0; mm < 2; ++mm) {
                    bf16x8 w = *(const bf16x8*)(lds + OFF_W1 + (((f * 10 + kk) * 2 + mm) * 64 + lane) * 16);
                    acc[mm] = __builtin_amdgcn_mfma_f32_32x32x16_bf16(w, a1[kk], acc[mm], 0, 0, 0);
                }

            // lrelu + pack: pk[mm][i] = bf16 pair of rows (reg 2i, 2i+1)
            unsigned pk[2][8];
            #pragma unroll
            for (int mm = 0; mm < 2; ++mm)
                #pragma unroll
                for (int i = 0; i < 8; ++i)
                    pk[mm][i] = cvt_pk(lrelu(acc[mm][2 * i]), lrelu(acc[mm][2 * i + 1]));

            // ---- layer 2: lane-pair redistribution, b2 as C-init
            f32x16 acc2[2];
            #pragma unroll
            for (int mm = 0; mm < 2; ++mm)
                #pragma unroll
                for (int q2 = 0; q2 < 4; ++q2) {
                    f32x4 v = *(const f32x4*)(lds + OFF_B2 + (f * 64 + mm * 32 + q2 * 8 + hi * 4) * 4);
                    acc2[mm][q2 * 4 + 0] = v[0]; acc2[mm][q2 * 4 + 1] = v[1];
                    acc2[mm][q2 * 4 + 2] = v[2]; acc2[mm][q2 * 4 + 3] = v[3];
                }
            #pragma unroll
            for (int kk2 = 0; kk2 < 4; ++kk2) {
                const int ms = kk2 >> 1, c = (kk2 & 1) * 4;
                unsigned pass0 = hi ? pk[ms][c + 0] : pk[ms][c + 2];
                unsigned pass1 = hi ? pk[ms][c + 1] : pk[ms][c + 3];
                unsigned sw0 = (unsigned)__shfl_xor((int)pass0, 32, 64);
                unsigned sw1 = (unsigned)__shfl_xor((int)pass1, 32, 64);
                union { bf16x8 v; unsigned u[4]; } bb;
                bb.u[0] = hi ? sw0 : pk[ms][c + 0];      // B[k=16kk2+8hi+j][edge]
                bb.u[1] = hi ? sw1 : pk[ms][c + 1];
                bb.u[2] = hi ? pk[ms][c + 2] : sw0;
                bb.u[3] = hi ? pk[ms][c + 3] : sw1;
                #pragma unroll
                for (int mm = 0; mm < 2; ++mm) {
                    bf16x8 w = *(const bf16x8*)(lds + OFF_W2 + (((f * 4 + kk2) * 2 + mm) * 64 + lane) * 16);
                    acc2[mm] = __builtin_amdgcn_mfma_f32_32x32x16_bf16(w, bb.v, acc2[mm], 0, 0, 0);
                }
            }

            // ---- layer 3: per-lane dot over 32 held rows, 1 pair-reduce
            float p = 0.f;
            #pragma unroll
            for (int mm = 0; mm < 2; ++mm)
                #pragma unroll
                for (int q2 = 0; q2 < 4; ++q2) {
                    f32x4 wv = *(const f32x4*)(lds + OFF_W3 + (f * 64 + mm * 32 + q2 * 8 + hi * 4) * 4);
                    #pragma unroll
                    for (int j = 0; j < 4; ++j)
                        p = fmaf(lrelu(acc2[mm][q2 * 4 + j]), wv[j], p);
                }
            p += __shfl_xor(p, 32, 64);

            if (lane < 32) {                             // coalesced 32-lane store
                int ee = tb + col;
                if (ee < n_edges) {
                    float val = p + (f == 0 ? b3v0 : b3v1);
                    if (__builtin_isnan(ea)) val = __builtin_nanf("");
                    out[f * n_edges + ee] = val;
                }
            }
        }

        t = tn; valid = vnext; af = af2; at = at2;       // wave-uniform
    }
}

extern "C" void kernel_launch(void* const* d_in, const int* in_sizes, int n_in,
                              void* d_out, int out_size, void* d_ws, size_t ws_size,
                              hipStream_t stream) {
    const float* edge_array = (const float*)d_in[0];
    const float* h_local    = (const float*)d_in[1];
    const float* h_global   = (const float*)d_in[2];
    const float* enc_local  = (const float*)d_in[3];
    const float* enc_global = (const float*)d_in[4];
    const float* W1 = (const float*)d_in[5];
    const float* b1 = (const float*)d_in[6];
    const float* W2 = (const float*)d_in[7];
    const float* b2 = (const float*)d_in[8];
    const float* W3 = (const float*)d_in[9];
    const float* b3 = (const float*)d_in[10];
    const int* addr_from = (const int*)d_in[11];
    const int* addr_to   = (const int*)d_in[12];
    int n_edges = in_sizes[11];
    int n_nodes = in_sizes[1] / 64;
    int n8 = n_nodes * 8;
    char* ws = (char*)d_ws;

    size_t off_ea0 = OFF_EA0;
    size_t off_hbf = (off_ea0 + (size_t)n_edges * 4 + 255) & ~(size_t)255;
    size_t need = off_hbf + (size_t)(n_nodes + 1) * 128;
    bool use_hbf = ws_size >= need;
    float* ea0 = (float*)(ws + off_ea0);
    short* hbf = (short*)(ws + off_hbf);

    int eb = (n_edges + 255) / 256;
    int hb = (n8 + 8 + 255) / 256;
    int prep_blocks = PREP_W_BLOCKS + eb + (use_hbf ? hb : 0);
    hipLaunchKernelGGL(prep_all, dim3(prep_blocks), dim3(256), 0, stream,
                       W1, b1, W2, b2, W3, b3, h_global, enc_global,
                       edge_array, h_local, n_edges, use_hbf ? n8 : 0, ea0, hbf, ws);

    int niters = (n_edges + 31) / 32;
    int nblk = 512;                                      // 2 persistent blocks/CU
    if (nblk * NWAVE > niters) nblk = (niters + NWAVE - 1) / NWAVE;
    if (use_hbf) {
        hipLaunchKernelGGL((main_kernel<true>), dim3(nblk), dim3(512), 0, stream,
                           h_local, enc_local, addr_from, addr_to,
                           ws, ea0, hbf, (float*)d_out, n_edges, n_nodes);
    } else {
        hipLaunchKernelGGL((main_kernel<false>), dim3(nblk), dim3(512), 0, stream,
                           h_local, enc_local, addr_from, addr_to,
                           ws, ea0, hbf, (float*)d_out, n_edges, n_nodes);
    }
}